// Round 3
// baseline (335.397 us; speedup 1.0000x reference)
//
#include <hip/hip_runtime.h>
#include <math.h>

// GCN 3-layer inference. N=100000, E=3200000, feats 128->4->2->1.
// R8:
//  - global-atomic degree counting in k_part (fire-and-forget, L2-resident 400KB)
//  - k_dinv: dinv + hs1=dinv*h1 + per-node CSR offsets (bucket-local scan of deg)
//  - k_deg_g1: merge -> CSR scatter -> FUSED layer-1 gather from just-written,
//    L1/L2-hot segment (k_gather1 dispatch + 15.6MB ssrc re-read eliminated;
//    LDS-atomic count pass eliminated -- offsets come from oc)
//  - merge bsearch: fixed 10-step branchless descent, 2-way interleaved (2x MLP)
//  - gathers g2/g3 + fused g1: 4-way unrolled independent loads (MLP instead of
//    4 serial rounds of 2-deep dependent chains)
// Edge pack: p = src | (dst&127)<<17  (src < 2^17).

#define TPB 256
#define CHUNK 4096
#define EPT (CHUNK / TPB)
#define BSZ 128             // nodes per bucket
#define SLAB2 4992          // per-bucket CSR capacity (mean 4096, sigma 64, +14 sigma)
#define NSMAX 1024

__global__ __launch_bounds__(TPB) void k_zero(int* __restrict__ deg, int n4) {
    int i = blockIdx.x * TPB + threadIdx.x;
    if (i < n4) ((int4*)deg)[i] = make_int4(0, 0, 0, 0);
}

// ---- k_part: counting sort of one 4096-edge chunk + deg atomics (+ GEMM blocks) ----
__global__ __launch_bounds__(TPB) void k_part(
    const int* __restrict__ src, const int* __restrict__ dst,
    unsigned int* __restrict__ slab, int* __restrict__ lstartT,
    int* __restrict__ deg,
    const float* __restrict__ x, const float* __restrict__ W1,
    float* __restrict__ h1,
    int NB, int NS, int E, int N)
{
    __shared__ int hist[NSMAX];
    __shared__ unsigned int sorted[CHUNK];
    __shared__ int wtot[4];
    int t = threadIdx.x;

    if (blockIdx.x >= NS) {
        // ---- fused GEMM: h1 = x @ W1 (unscaled), quad-per-node ----
        float* Ws = (float*)sorted;  // alias: sort path never runs here
        for (int i = t; i < 512; i += TPB) Ws[i] = W1[i];
        __syncthreads();
        int tt = (blockIdx.x - NS) * TPB + t;
        int v = tt >> 2, p = tt & 3;
        if (v >= N) return;
        const float4* xr = (const float4*)(x + (size_t)v * 128);
        float a0 = 0.f, a1 = 0.f, a2 = 0.f, a3 = 0.f;
#pragma unroll
        for (int i = 0; i < 8; ++i) {
            int cc = p + i * 4;
            float4 xx = xr[cc];
            const float* wv = &Ws[cc * 16];
            a0 += xx.x*wv[0] + xx.y*wv[4] + xx.z*wv[8]  + xx.w*wv[12];
            a1 += xx.x*wv[1] + xx.y*wv[5] + xx.z*wv[9]  + xx.w*wv[13];
            a2 += xx.x*wv[2] + xx.y*wv[6] + xx.z*wv[10] + xx.w*wv[14];
            a3 += xx.x*wv[3] + xx.y*wv[7] + xx.z*wv[11] + xx.w*wv[15];
        }
        a0 += __shfl_xor(a0,1); a0 += __shfl_xor(a0,2);
        a1 += __shfl_xor(a1,1); a1 += __shfl_xor(a1,2);
        a2 += __shfl_xor(a2,1); a2 += __shfl_xor(a2,2);
        a3 += __shfl_xor(a3,1); a3 += __shfl_xor(a3,2);
        if (p == 0) ((float4*)h1)[v] = make_float4(a0, a1, a2, a3);
        return;
    }

    int base = blockIdx.x * CHUNK;
    int n = min(CHUNK, E - base);
    for (int i = t; i < NSMAX; i += TPB) hist[i] = 0;
    __syncthreads();
    unsigned int meta[EPT];   // d<<13 | lp   (lp < 4096 fits 13 bits; d < 2^17)
#pragma unroll
    for (int k = 0; k < EPT; ++k) {
        int li = k * TPB + t;
        if (li < n) {
            int d = dst[base + li];
            atomicAdd(&deg[d], 1);                 // fire-and-forget, L2-resident
            int lp = atomicAdd(&hist[d >> 7], 1);
            meta[k] = ((unsigned)d << 13) | (unsigned)lp;
        } else meta[k] = 0xFFFFFFFFu;
    }
    __syncthreads();
    // exclusive scan hist[1024]: thread t owns bins 4t..4t+3, wave scan + cross-wave
    int lane = t & 63, w = t >> 6;
    int q0 = hist[4*t], q1 = hist[4*t+1], q2 = hist[4*t+2], q3 = hist[4*t+3];
    int pq = q0 + q1 + q2 + q3, xs = pq;
    for (int d = 1; d < 64; d <<= 1) { int y = __shfl_up(xs, d); if (lane >= d) xs += y; }
    if (lane == 63) wtot[w] = xs;
    __syncthreads();
    int woff = 0;
#pragma unroll
    for (int i = 0; i < 4; ++i) if (i < w) woff += wtot[i];
    int e0 = woff + xs - pq;
    hist[4*t]   = e0;
    hist[4*t+1] = e0 + q0;
    hist[4*t+2] = e0 + q0 + q1;
    hist[4*t+3] = e0 + q0 + q1 + q2;
    __syncthreads();
#pragma unroll
    for (int k = 0; k < EPT; ++k) {
        if (meta[k] != 0xFFFFFFFFu) {
            unsigned m = meta[k];
            int d = (int)(m >> 13);
            int lp = (int)(m & 0x1FFFu);
            unsigned pk = (unsigned)src[base + k*TPB + t] | ((unsigned)(d & 127) << 17);
            sorted[hist[d >> 7] + lp] = pk;
        }
    }
    __syncthreads();
    const uint4* s4 = (const uint4*)sorted;
    uint4* g4 = (uint4*)(slab + (size_t)base);
    for (int i = t; i < CHUNK / 4; i += TPB) g4[i] = s4[i];
    for (int i = t; i < NB + 1; i += TPB)
        lstartT[(size_t)i * NS + blockIdx.x] = hist[i];
}

// ---- k_dinv: dinv, hs1 = dinv*h1, per-node CSR offsets from bucket-local scan ----
__global__ __launch_bounds__(TPB) void k_dinv(
    const int* __restrict__ deg, const float* __restrict__ h1,
    float* __restrict__ dinv, float* __restrict__ hs1,
    int2* __restrict__ oc, int N)
{
    __shared__ int wt[4];
    int t = threadIdx.x;
    int v = blockIdx.x * TPB + t;               // block = 2 aligned buckets of 128
    int dg = (v < N) ? deg[v] : 0;
    int lane = t & 63, w = t >> 6;
    int xc = dg;
    for (int d = 1; d < 64; d <<= 1) { int y = __shfl_up(xc, d); if (lane >= d) xc += y; }
    if (lane == 63) wt[w] = xc;
    __syncthreads();
    // bucket-local exclusive offset: waves {0,1} = bucket A, {2,3} = bucket B
    int excl = xc - dg + ((w & 1) ? wt[w - 1] : 0);
    if (v < N) {
        int b = v >> 7;
        oc[v] = make_int2(b * SLAB2 + excl, dg);
        float di = rsqrtf((float)(dg + 1));
        dinv[v] = di;
        float4 hv = ((const float4*)h1)[v];
        ((float4*)hs1)[v] = make_float4(di*hv.x, di*hv.y, di*hv.z, di*hv.w);
    }
}

// ---- k_deg_g1: merge -> CSR scatter -> fused layer-1 gather + epilogue ----
__global__ __launch_bounds__(TPB) void k_deg_g1(
    const unsigned int* __restrict__ slab, const int* __restrict__ lstartT,
    int* __restrict__ ssrc, const int2* __restrict__ oc,
    const float* __restrict__ hs1, const float* __restrict__ dinv,
    const float* __restrict__ b1, const float* __restrict__ W2,
    float* __restrict__ hs2,
    int NS, int NB, int N)
{
    __shared__ unsigned int pl[SLAB2];   // 19968 B
    __shared__ int sstart[NSMAX];
    __shared__ int slen[NSMAX];          // after scan: exclusive starts (pad = total)
    __shared__ int excl0[BSZ];
    __shared__ int cnt0[BSZ];
    __shared__ int cur[BSZ];
    __shared__ int wtot[4];
    int t = threadIdx.x, b = blockIdx.x;

    for (int j = t; j < NSMAX; j += TPB) {
        int st = 0, len = 0;
        if (j < NS) {
            st  = lstartT[(size_t)b * NS + j];
            len = lstartT[(size_t)(b + 1) * NS + j] - st;
        }
        sstart[j] = st;
        slen[j] = len;
    }
    if (t < BSZ) {
        int v = (b << 7) + t;
        int2 o = (v < N) ? oc[v] : make_int2(b * SLAB2, 0);
        int e = o.x - b * SLAB2;
        excl0[t] = e; cnt0[t] = o.y; cur[t] = e;
    }
    __syncthreads();
    // exclusive scan slen[1024]: thread owns 4, wave scan
    int lane = t & 63, w = t >> 6;
    int s0 = slen[4*t], s1 = slen[4*t+1], s2 = slen[4*t+2], s3 = slen[4*t+3];
    int pq = s0 + s1 + s2 + s3, xs = pq;
    for (int d = 1; d < 64; d <<= 1) { int y = __shfl_up(xs, d); if (lane >= d) xs += y; }
    if (lane == 63) wtot[w] = xs;
    __syncthreads();
    int woff = 0, tot = 0;
#pragma unroll
    for (int i = 0; i < 4; ++i) { int z = wtot[i]; tot += z; if (i < w) woff += z; }
    int e0 = woff + xs - pq;
    slen[4*t]   = e0;
    slen[4*t+1] = e0 + s0;
    slen[4*t+2] = e0 + s0 + s1;
    slen[4*t+3] = e0 + s0 + s1 + s2;
    __syncthreads();
    int total = min(tot, SLAB2);
    // merge: fixed 10-step branchless bsearch, 2-way interleaved for MLP
    for (int i0 = t; i0 < total; i0 += 2*TPB) {
        int i1 = i0 + TPB;
        bool has1 = (i1 < total);
        int lo0 = 0, lo1 = 0;
#pragma unroll
        for (int s = 512; s > 0; s >>= 1) {
            if (slen[lo0 + s] <= i0) lo0 += s;
            if (has1 && slen[lo1 + s] <= i1) lo1 += s;
        }
        pl[i0] = slab[(size_t)lo0 * CHUNK + sstart[lo0] + (i0 - slen[lo0])];
        if (has1)
            pl[i1] = slab[(size_t)lo1 * CHUNK + sstart[lo1] + (i1 - slen[lo1])];
    }
    __syncthreads();
    // counting-sort scatter into this bucket's CSR region (stays L1/L2-hot)
    int* sb = ssrc + (size_t)b * SLAB2;
    for (int i = t; i < total; i += TPB) {
        unsigned pk = pl[i];
        int pos = atomicAdd(&cur[(pk >> 17) & 127], 1);
        sb[pos] = (int)(pk & 0x1FFFFu);
    }
    __syncthreads();
    // fused layer-1 gather: 4 passes x (32 nodes x 8 lanes), 4-way unrolled MLP
    const float4* H = (const float4*)hs1;
#pragma unroll
    for (int ps = 0; ps < 4; ++ps) {
        int vl = ps * 32 + (t >> 3);
        int p = t & 7;
        int v = (b << 7) + vl;
        int c = cnt0[vl];
        int b0 = excl0[vl];
        float4 acc = make_float4(0.f, 0.f, 0.f, 0.f);
        for (int i = p; i < c; i += 32) {
            bool m1 = (i + 8 < c), m2 = (i + 16 < c), m3 = (i + 24 < c);
            int s0v = sb[b0 + i];
            int s1v = sb[b0 + (m1 ? i + 8  : i)];
            int s2v = sb[b0 + (m2 ? i + 16 : i)];
            int s3v = sb[b0 + (m3 ? i + 24 : i)];
            float4 h0 = H[s0v], h1v = H[s1v], h2 = H[s2v], h3 = H[s3v];
            acc.x += h0.x; acc.y += h0.y; acc.z += h0.z; acc.w += h0.w;
            if (m1) { acc.x += h1v.x; acc.y += h1v.y; acc.z += h1v.z; acc.w += h1v.w; }
            if (m2) { acc.x += h2.x;  acc.y += h2.y;  acc.z += h2.z;  acc.w += h2.w; }
            if (m3) { acc.x += h3.x;  acc.y += h3.y;  acc.z += h3.z;  acc.w += h3.w; }
        }
        acc.x += __shfl_xor(acc.x,1); acc.x += __shfl_xor(acc.x,2); acc.x += __shfl_xor(acc.x,4);
        acc.y += __shfl_xor(acc.y,1); acc.y += __shfl_xor(acc.y,2); acc.y += __shfl_xor(acc.y,4);
        acc.z += __shfl_xor(acc.z,1); acc.z += __shfl_xor(acc.z,2); acc.z += __shfl_xor(acc.z,4);
        acc.w += __shfl_xor(acc.w,1); acc.w += __shfl_xor(acc.w,2); acc.w += __shfl_xor(acc.w,4);
        if (p == 0 && v < N) {
            float4 hv = H[v];
            float di = dinv[v];
            float o0 = fmaxf(di * (acc.x + hv.x) + b1[0], 0.f);
            float o1 = fmaxf(di * (acc.y + hv.y) + b1[1], 0.f);
            float o2 = fmaxf(di * (acc.z + hv.z) + b1[2], 0.f);
            float o3 = fmaxf(di * (acc.w + hv.w) + b1[3], 0.f);
            float g0 = o0 * W2[0] + o1 * W2[2] + o2 * W2[4] + o3 * W2[6];
            float g1 = o0 * W2[1] + o1 * W2[3] + o2 * W2[5] + o3 * W2[7];
            ((float2*)hs2)[v] = make_float2(di * g0, di * g1);
        }
    }
}

// ---- gathers 2,3: 8 lanes/node, 4-way unrolled MLP ----
__global__ __launch_bounds__(TPB) void k_gather2(
    const int2* __restrict__ oc, const int* __restrict__ ssrc,
    const float* __restrict__ hs2, const float* __restrict__ dinv,
    const float* __restrict__ b2, const float* __restrict__ W3,
    float* __restrict__ hs3, int n) {
    int t = blockIdx.x * TPB + threadIdx.x;
    int v = t >> 3, p = t & 7;
    if (v >= n) return;
    int2 ocv = oc[v];
    int base = ocv.x, c = ocv.y;
    const float2* H = (const float2*)hs2;
    float2 acc = make_float2(0.f, 0.f);
    for (int i = p; i < c; i += 32) {
        bool m1 = (i + 8 < c), m2 = (i + 16 < c), m3 = (i + 24 < c);
        int s0 = ssrc[base + i];
        int s1 = ssrc[base + (m1 ? i + 8  : i)];
        int s2 = ssrc[base + (m2 ? i + 16 : i)];
        int s3 = ssrc[base + (m3 ? i + 24 : i)];
        float2 h0 = H[s0], h1 = H[s1], h2 = H[s2], h3 = H[s3];
        acc.x += h0.x; acc.y += h0.y;
        if (m1) { acc.x += h1.x; acc.y += h1.y; }
        if (m2) { acc.x += h2.x; acc.y += h2.y; }
        if (m3) { acc.x += h3.x; acc.y += h3.y; }
    }
    acc.x += __shfl_xor(acc.x,1); acc.x += __shfl_xor(acc.x,2); acc.x += __shfl_xor(acc.x,4);
    acc.y += __shfl_xor(acc.y,1); acc.y += __shfl_xor(acc.y,2); acc.y += __shfl_xor(acc.y,4);
    if (p == 0) {
        float2 hv = H[v];
        float di = dinv[v];
        float o0 = fmaxf(di * (acc.x + hv.x) + b2[0], 0.f);
        float o1 = fmaxf(di * (acc.y + hv.y) + b2[1], 0.f);
        float h3v = o0 * W3[0] + o1 * W3[1];
        hs3[v] = di * h3v;
    }
}

__global__ __launch_bounds__(TPB) void k_gather3(
    const int2* __restrict__ oc, const int* __restrict__ ssrc,
    const float* __restrict__ hs3, const float* __restrict__ dinv,
    const float* __restrict__ b3, float* __restrict__ out, int n) {
    int t = blockIdx.x * TPB + threadIdx.x;
    int v = t >> 3, p = t & 7;
    if (v >= n) return;
    int2 ocv = oc[v];
    int base = ocv.x, c = ocv.y;
    float acc = 0.f;
    for (int i = p; i < c; i += 32) {
        bool m1 = (i + 8 < c), m2 = (i + 16 < c), m3 = (i + 24 < c);
        int s0 = ssrc[base + i];
        int s1 = ssrc[base + (m1 ? i + 8  : i)];
        int s2 = ssrc[base + (m2 ? i + 16 : i)];
        int s3 = ssrc[base + (m3 ? i + 24 : i)];
        float h0 = hs3[s0], h1 = hs3[s1], h2 = hs3[s2], h3 = hs3[s3];
        acc += h0;
        if (m1) acc += h1;
        if (m2) acc += h2;
        if (m3) acc += h3;
    }
    acc += __shfl_xor(acc, 1); acc += __shfl_xor(acc, 2); acc += __shfl_xor(acc, 4);
    if (p == 0) {
        float di = dinv[v];
        float agg = di * (acc + hs3[v]) + b3[0];
        out[v] = 1.0f / (1.0f + __expf(-agg));
    }
}

extern "C" void kernel_launch(void* const* d_in, const int* in_sizes, int n_in,
                              void* d_out, int out_size, void* d_ws, size_t ws_size,
                              hipStream_t stream) {
    const float* x  = (const float*)d_in[0];
    const int* ei   = (const int*)d_in[1];
    const float* W1 = (const float*)d_in[2];
    const float* b1 = (const float*)d_in[3];
    const float* W2 = (const float*)d_in[4];
    const float* b2 = (const float*)d_in[5];
    const float* W3 = (const float*)d_in[6];
    const float* b3 = (const float*)d_in[7];
    float* out = (float*)d_out;

    const int N = in_sizes[0] / 128;
    const int E = in_sizes[1] / 2;
    const int* src = ei;
    const int* dst = ei + E;

    const int NS = (E + CHUNK - 1) / CHUNK;   // 782 chunks
    const int NB = (N + BSZ - 1) / BSZ;       // 782 buckets of 128 nodes

    // ws carve (~38 MB; ws is 256 MiB).
    char* w = (char*)d_ws;
    auto carve = [&](size_t bytes) { char* p = w; w += (bytes + 15) & ~(size_t)15; return p; };
    unsigned int* slab = (unsigned int*)carve((size_t)NS * CHUNK * 4);
    int* lstartT       = (int*)carve((size_t)(NB + 1) * NS * 4);
    int* ssrc          = (int*)carve((size_t)NB * SLAB2 * 4 + 128);
    int2* oc           = (int2*)carve((size_t)N * 8);
    int* deg           = (int*)carve((size_t)((N + 3) & ~3) * 4);
    float* dinv        = (float*)carve((size_t)N * 4);
    float* h1          = (float*)carve((size_t)4 * N * 4);
    float* hs1         = (float*)carve((size_t)4 * N * 4);
    float* hs2         = (float*)carve((size_t)2 * N * 4);
    float* hs3         = (float*)carve((size_t)N * 4);

    const int n4   = (N + 3) / 4;
    const int nbz  = (n4 + TPB - 1) / TPB;
    const int nb1  = (4 * N + TPB - 1) / TPB;  // 1563 GEMM blocks
    const int nbN  = (N + TPB - 1) / TPB;      // 391
    const int nbN8 = (8 * N + TPB - 1) / TPB;  // 3125

    k_zero   <<<nbz, TPB, 0, stream>>>(deg, n4);
    k_part   <<<NS + nb1, TPB, 0, stream>>>(src, dst, slab, lstartT, deg, x, W1, h1, NB, NS, E, N);
    k_dinv   <<<nbN, TPB, 0, stream>>>(deg, h1, dinv, hs1, oc, N);
    k_deg_g1 <<<NB, TPB, 0, stream>>>(slab, lstartT, ssrc, oc, hs1, dinv, b1, W2, hs2, NS, NB, N);
    k_gather2<<<nbN8, TPB, 0, stream>>>(oc, ssrc, hs2, dinv, b2, W3, hs3, N);
    k_gather3<<<nbN8, TPB, 0, stream>>>(oc, ssrc, hs3, dinv, b3, out, N);
}

// Round 4
// 306.351 us; speedup vs baseline: 1.0948x; 1.0948x over previous
//
#include <hip/hip_runtime.h>
#include <math.h>

// GCN 3-layer inference. N=100000, E=3200000, feats 128->4->2->1.
// R9:
//  - revert R8's global deg atomics (measured: 3.2M random device-scope atomics
//    cost ~110us and 125MB of write traffic -- they resolve at the fabric, not L2)
//  - DROP the per-node CSR entirely: gathers only need per-BUCKET edge grouping.
//    k_merge writes a bucket-grouped packed edge list pkd (coalesced uint4), and
//    g-kernels accumulate into 128 per-node LDS float accumulators (ds_add_f32).
//    Deleted: oc array, per-node offset scan, atomic CSR scatter, 8-lane segment
//    walks (replaced by 16 independent coalesced edges/thread).
//  - k_merge uses merge-path: one 10-step bsearch per thread + incremental walk
//    over a per-thread contiguous range (odd stride -> no LDS write conflicts).
// Edge pack: p = src | (dst&127)<<17  (src < 2^17).

#define TPB 256
#define CHUNK 4096
#define EPT (CHUNK / TPB)
#define BSZ 128             // nodes per bucket
#define SLAB2 4992          // per-bucket edge capacity (mean 4096, sigma 64, +14 sigma)
#define NSMAX 1024

// ---- k_part: counting sort of one 4096-edge chunk (+ fused GEMM blocks) ----
__global__ __launch_bounds__(TPB) void k_part(
    const int* __restrict__ src, const int* __restrict__ dst,
    unsigned int* __restrict__ slab, int* __restrict__ lstartT,
    const float* __restrict__ x, const float* __restrict__ W1,
    float* __restrict__ h1,
    int NB, int NS, int E, int N)
{
    __shared__ int hist[NSMAX];
    __shared__ unsigned int sorted[CHUNK];
    __shared__ int wtot[4];
    int t = threadIdx.x;

    if (blockIdx.x >= NS) {
        // ---- fused GEMM: h1 = x @ W1 (unscaled), quad-per-node ----
        float* Ws = (float*)sorted;  // alias: sort path never runs here
        for (int i = t; i < 512; i += TPB) Ws[i] = W1[i];
        __syncthreads();
        int tt = (blockIdx.x - NS) * TPB + t;
        int v = tt >> 2, p = tt & 3;
        if (v >= N) return;
        const float4* xr = (const float4*)(x + (size_t)v * 128);
        float a0 = 0.f, a1 = 0.f, a2 = 0.f, a3 = 0.f;
#pragma unroll
        for (int i = 0; i < 8; ++i) {
            int cc = p + i * 4;
            float4 xx = xr[cc];
            const float* wv = &Ws[cc * 16];
            a0 += xx.x*wv[0] + xx.y*wv[4] + xx.z*wv[8]  + xx.w*wv[12];
            a1 += xx.x*wv[1] + xx.y*wv[5] + xx.z*wv[9]  + xx.w*wv[13];
            a2 += xx.x*wv[2] + xx.y*wv[6] + xx.z*wv[10] + xx.w*wv[14];
            a3 += xx.x*wv[3] + xx.y*wv[7] + xx.z*wv[11] + xx.w*wv[15];
        }
        a0 += __shfl_xor(a0,1); a0 += __shfl_xor(a0,2);
        a1 += __shfl_xor(a1,1); a1 += __shfl_xor(a1,2);
        a2 += __shfl_xor(a2,1); a2 += __shfl_xor(a2,2);
        a3 += __shfl_xor(a3,1); a3 += __shfl_xor(a3,2);
        if (p == 0) ((float4*)h1)[v] = make_float4(a0, a1, a2, a3);
        return;
    }

    int base = blockIdx.x * CHUNK;
    int n = min(CHUNK, E - base);
    for (int i = t; i < NSMAX; i += TPB) hist[i] = 0;
    __syncthreads();
    unsigned int meta[EPT];   // d<<13 | lp   (lp < 4096 fits 13 bits; d < 2^17)
#pragma unroll
    for (int k = 0; k < EPT; ++k) {
        int li = k * TPB + t;
        if (li < n) {
            int d = dst[base + li];
            int lp = atomicAdd(&hist[d >> 7], 1);
            meta[k] = ((unsigned)d << 13) | (unsigned)lp;
        } else meta[k] = 0xFFFFFFFFu;
    }
    __syncthreads();
    // exclusive scan hist[1024]: thread t owns bins 4t..4t+3, wave scan + cross-wave
    int lane = t & 63, w = t >> 6;
    int q0 = hist[4*t], q1 = hist[4*t+1], q2 = hist[4*t+2], q3 = hist[4*t+3];
    int pq = q0 + q1 + q2 + q3, xs = pq;
    for (int d = 1; d < 64; d <<= 1) { int y = __shfl_up(xs, d); if (lane >= d) xs += y; }
    if (lane == 63) wtot[w] = xs;
    __syncthreads();
    int woff = 0;
#pragma unroll
    for (int i = 0; i < 4; ++i) if (i < w) woff += wtot[i];
    int e0 = woff + xs - pq;
    hist[4*t]   = e0;
    hist[4*t+1] = e0 + q0;
    hist[4*t+2] = e0 + q0 + q1;
    hist[4*t+3] = e0 + q0 + q1 + q2;
    __syncthreads();
#pragma unroll
    for (int k = 0; k < EPT; ++k) {
        if (meta[k] != 0xFFFFFFFFu) {
            unsigned m = meta[k];
            int d = (int)(m >> 13);
            int lp = (int)(m & 0x1FFFu);
            unsigned pk = (unsigned)src[base + k*TPB + t] | ((unsigned)(d & 127) << 17);
            sorted[hist[d >> 7] + lp] = pk;
        }
    }
    __syncthreads();
    const uint4* s4 = (const uint4*)sorted;
    uint4* g4 = (uint4*)(slab + (size_t)base);
    for (int i = t; i < CHUNK / 4; i += TPB) g4[i] = s4[i];
    for (int i = t; i < NB + 1; i += TPB)
        lstartT[(size_t)i * NS + blockIdx.x] = hist[i];
}

// ---- k_merge: merge-path -> pkd (coalesced) + LDS degree count + dinv + hs1 ----
__global__ __launch_bounds__(TPB) void k_merge(
    const unsigned int* __restrict__ slab, const int* __restrict__ lstartT,
    unsigned int* __restrict__ pkd, int* __restrict__ bcnt,
    const float* __restrict__ h1, float* __restrict__ dinv, float* __restrict__ hs1,
    int NS, int NB, int N)
{
    __shared__ unsigned int pl[SLAB2];   // 19968 B
    __shared__ int sstart[NSMAX];
    __shared__ int slen[NSMAX];          // after scan: exclusive starts (pad = total)
    __shared__ int c[BSZ];
    __shared__ int wtot[4];
    int t = threadIdx.x, b = blockIdx.x;
    if (t < BSZ) c[t] = 0;
    for (int j = t; j < NSMAX; j += TPB) {
        int st = 0, len = 0;
        if (j < NS) {
            st  = lstartT[(size_t)b * NS + j];
            len = lstartT[(size_t)(b + 1) * NS + j] - st;
        }
        sstart[j] = st;
        slen[j] = len;
    }
    __syncthreads();
    // exclusive scan slen[1024]: thread owns 4, wave scan
    int lane = t & 63, w = t >> 6;
    int s0 = slen[4*t], s1 = slen[4*t+1], s2 = slen[4*t+2], s3 = slen[4*t+3];
    int pq = s0 + s1 + s2 + s3, xs = pq;
    for (int d = 1; d < 64; d <<= 1) { int y = __shfl_up(xs, d); if (lane >= d) xs += y; }
    if (lane == 63) wtot[w] = xs;
    __syncthreads();
    int woff = 0, tot = 0;
#pragma unroll
    for (int i = 0; i < 4; ++i) { int z = wtot[i]; tot += z; if (i < w) woff += z; }
    int e0 = woff + xs - pq;
    slen[4*t]   = e0;
    slen[4*t+1] = e0 + s0;
    slen[4*t+2] = e0 + s0 + s1;
    slen[4*t+3] = e0 + s0 + s1 + s2;
    __syncthreads();
    int total = min(tot, SLAB2);
    // merge-path: per-thread contiguous range [i0,i1); odd stride dodges LDS
    // write-bank aliasing; one bsearch then incremental segment walk.
    int per = ((total + TPB - 1) / TPB) | 1;
    int i0 = t * per, i1 = min(i0 + per, total);
    if (i0 < i1) {
        int lo = 0;
#pragma unroll
        for (int s = 512; s > 0; s >>= 1)
            if (slen[lo + s] <= i0) lo += s;
        for (int i = i0; i < i1; ++i) {
            while (slen[lo + 1] <= i) ++lo;     // sentinel slen[NS..] == total
            unsigned v = slab[(size_t)lo * CHUNK + sstart[lo] + (i - slen[lo])];
            pl[i] = v;
            atomicAdd(&c[(v >> 17) & 127], 1);
        }
    }
    __syncthreads();
    // coalesced uint4 copy pl -> pkd (tail slots beyond total are never read)
    int n4 = (total + 3) >> 2;
    const uint4* p4 = (const uint4*)pl;
    uint4* g4 = (uint4*)(pkd + (size_t)b * SLAB2);
    for (int i = t; i < n4; i += TPB) g4[i] = p4[i];
    if (t < BSZ) {
        int v = (b << 7) + t;
        if (v < N) {
            int dg = c[t];
            float di = rsqrtf((float)(dg + 1));
            dinv[v] = di;
            float4 hv = ((const float4*)h1)[v];
            ((float4*)hs1)[v] = make_float4(di*hv.x, di*hv.y, di*hv.z, di*hv.w);
        }
    }
    if (t == 0) bcnt[b] = total;
}

// ---- g-kernels: one block per bucket, edge-parallel, LDS float accumulation ----
__global__ __launch_bounds__(TPB) void k_g1(
    const unsigned int* __restrict__ pkd, const int* __restrict__ bcnt,
    const float* __restrict__ hs1, const float* __restrict__ dinv,
    const float* __restrict__ b1, const float* __restrict__ W2,
    float* __restrict__ hs2, int N)
{
    __shared__ float acc[BSZ][4];
    int t = threadIdx.x, b = blockIdx.x;
    if (t < BSZ) { acc[t][0] = 0.f; acc[t][1] = 0.f; acc[t][2] = 0.f; acc[t][3] = 0.f; }
    __syncthreads();
    int total = bcnt[b];
    const unsigned int* pb = pkd + (size_t)b * SLAB2;
    const float4* H = (const float4*)hs1;
#pragma unroll 4
    for (int i = t; i < total; i += TPB) {
        unsigned p = pb[i];
        int s = (int)(p & 0x1FFFFu), dl = (int)((p >> 17) & 127u);
        float4 h = H[s];
        atomicAdd(&acc[dl][0], h.x);
        atomicAdd(&acc[dl][1], h.y);
        atomicAdd(&acc[dl][2], h.z);
        atomicAdd(&acc[dl][3], h.w);
    }
    __syncthreads();
    if (t < BSZ) {
        int v = (b << 7) + t;
        if (v < N) {
            float4 hv = H[v];
            float di = dinv[v];
            float o0 = fmaxf(di * (acc[t][0] + hv.x) + b1[0], 0.f);
            float o1 = fmaxf(di * (acc[t][1] + hv.y) + b1[1], 0.f);
            float o2 = fmaxf(di * (acc[t][2] + hv.z) + b1[2], 0.f);
            float o3 = fmaxf(di * (acc[t][3] + hv.w) + b1[3], 0.f);
            float g0 = o0 * W2[0] + o1 * W2[2] + o2 * W2[4] + o3 * W2[6];
            float g1 = o0 * W2[1] + o1 * W2[3] + o2 * W2[5] + o3 * W2[7];
            ((float2*)hs2)[v] = make_float2(di * g0, di * g1);
        }
    }
}

__global__ __launch_bounds__(TPB) void k_g2(
    const unsigned int* __restrict__ pkd, const int* __restrict__ bcnt,
    const float* __restrict__ hs2, const float* __restrict__ dinv,
    const float* __restrict__ b2, const float* __restrict__ W3,
    float* __restrict__ hs3, int N)
{
    __shared__ float acc[BSZ][2];
    int t = threadIdx.x, b = blockIdx.x;
    if (t < BSZ) { acc[t][0] = 0.f; acc[t][1] = 0.f; }
    __syncthreads();
    int total = bcnt[b];
    const unsigned int* pb = pkd + (size_t)b * SLAB2;
    const float2* H = (const float2*)hs2;
#pragma unroll 4
    for (int i = t; i < total; i += TPB) {
        unsigned p = pb[i];
        int s = (int)(p & 0x1FFFFu), dl = (int)((p >> 17) & 127u);
        float2 h = H[s];
        atomicAdd(&acc[dl][0], h.x);
        atomicAdd(&acc[dl][1], h.y);
    }
    __syncthreads();
    if (t < BSZ) {
        int v = (b << 7) + t;
        if (v < N) {
            float2 hv = H[v];
            float di = dinv[v];
            float o0 = fmaxf(di * (acc[t][0] + hv.x) + b2[0], 0.f);
            float o1 = fmaxf(di * (acc[t][1] + hv.y) + b2[1], 0.f);
            float h3v = o0 * W3[0] + o1 * W3[1];
            hs3[v] = di * h3v;
        }
    }
}

__global__ __launch_bounds__(TPB) void k_g3(
    const unsigned int* __restrict__ pkd, const int* __restrict__ bcnt,
    const float* __restrict__ hs3, const float* __restrict__ dinv,
    const float* __restrict__ b3, float* __restrict__ out, int N)
{
    __shared__ float acc[BSZ];
    int t = threadIdx.x, b = blockIdx.x;
    if (t < BSZ) acc[t] = 0.f;
    __syncthreads();
    int total = bcnt[b];
    const unsigned int* pb = pkd + (size_t)b * SLAB2;
#pragma unroll 4
    for (int i = t; i < total; i += TPB) {
        unsigned p = pb[i];
        int s = (int)(p & 0x1FFFFu), dl = (int)((p >> 17) & 127u);
        atomicAdd(&acc[dl], hs3[s]);
    }
    __syncthreads();
    if (t < BSZ) {
        int v = (b << 7) + t;
        if (v < N) {
            float di = dinv[v];
            float agg = di * (acc[t] + hs3[v]) + b3[0];
            out[v] = 1.0f / (1.0f + __expf(-agg));
        }
    }
}

extern "C" void kernel_launch(void* const* d_in, const int* in_sizes, int n_in,
                              void* d_out, int out_size, void* d_ws, size_t ws_size,
                              hipStream_t stream) {
    const float* x  = (const float*)d_in[0];
    const int* ei   = (const int*)d_in[1];
    const float* W1 = (const float*)d_in[2];
    const float* b1 = (const float*)d_in[3];
    const float* W2 = (const float*)d_in[4];
    const float* b2 = (const float*)d_in[5];
    const float* W3 = (const float*)d_in[6];
    const float* b3 = (const float*)d_in[7];
    float* out = (float*)d_out;

    const int N = in_sizes[0] / 128;
    const int E = in_sizes[1] / 2;
    const int* src = ei;
    const int* dst = ei + E;

    const int NS = (E + CHUNK - 1) / CHUNK;   // 782 chunks
    const int NB = (N + BSZ - 1) / BSZ;       // 782 buckets of 128 nodes

    // ws carve (~35 MB; ws is 256 MiB).
    char* w = (char*)d_ws;
    auto carve = [&](size_t bytes) { char* p = w; w += (bytes + 15) & ~(size_t)15; return p; };
    unsigned int* slab = (unsigned int*)carve((size_t)NS * CHUNK * 4);
    int* lstartT       = (int*)carve((size_t)(NB + 1) * NS * 4);
    unsigned int* pkd  = (unsigned int*)carve((size_t)NB * SLAB2 * 4);
    int* bcnt          = (int*)carve((size_t)NB * 4);
    float* dinv        = (float*)carve((size_t)N * 4);
    float* h1          = (float*)carve((size_t)4 * N * 4);
    float* hs1         = (float*)carve((size_t)4 * N * 4);
    float* hs2         = (float*)carve((size_t)2 * N * 4);
    float* hs3         = (float*)carve((size_t)N * 4);

    const int nb1 = (4 * N + TPB - 1) / TPB;  // 1563 GEMM blocks

    k_part <<<NS + nb1, TPB, 0, stream>>>(src, dst, slab, lstartT, x, W1, h1, NB, NS, E, N);
    k_merge<<<NB, TPB, 0, stream>>>(slab, lstartT, pkd, bcnt, h1, dinv, hs1, NS, NB, N);
    k_g1   <<<NB, TPB, 0, stream>>>(pkd, bcnt, hs1, dinv, b1, W2, hs2, N);
    k_g2   <<<NB, TPB, 0, stream>>>(pkd, bcnt, hs2, dinv, b2, W3, hs3, N);
    k_g3   <<<NB, TPB, 0, stream>>>(pkd, bcnt, hs3, dinv, b3, out, N);
}